// Round 5
// baseline (165.845 us; speedup 1.0000x reference)
//
#include <hip/hip_runtime.h>

// CurvatureLoss3D — 2.5D LDS-tiled, register z-sliding, software-pipelined
// staging, PACKED-FP32 curvature math (v_pk_fma_f32 via float2 ext-vectors).
//
// Packing trick: each thread owns 4 x-adjacent voxels; voxels are paired
// stride-2 (pair p = voxels {p, p+2}). With q[k] = (r[k], r[k+2]) the packed
// stencil tap at dx for pair p is exactly q[dx+p] — no overlap, no repacking
// movs inside the math. All stencil/curvature mul/add/fma run 2 voxels/instr.
// sqrt/rcp and min/max (no packed f32 min/max on CDNA) stay per-element.

typedef float v2f __attribute__((ext_vector_type(2)));

constexpr int DIM  = 192;
constexpr int ODIM = 190;
constexpr int TX = 32, TY = 32, CZ = 7;
constexpr int NTX = 6, NTY = 6, NTZ = 28;   // 28*7 = 196 >= 190
constexpr int HX = 34, HY = 34;
constexpr int LX = 36;                      // padded LDS row stride (144 B = 9x16)
constexpr int NELEM = HX * HY;              // 1156
constexpr int NBLOCKS = 2 * NTZ * NTY * NTX;  // 2016 (<= full-residency capacity)

struct Slice {
    v2f   q[3][4];          // rows y..y+2; q[dy][k] = (r[k], r[k+2])
    float mn[6], mx[6];     // per-column min/max over the 3 rows
};

__global__ __launch_bounds__(256, 4) void curv_main(const float* __restrict__ phi,
                                                    double* __restrict__ acc,
                                                    int use_partials) {
    __shared__ __align__(16) float tile[3][HY][LX];

    int bx = blockIdx.x;
    const int tx = bx % NTX; bx /= NTX;
    const int ty = bx % NTY; bx /= NTY;
    const int tz = bx % NTZ; bx /= NTZ;
    const int n  = bx;

    const int xbase = tx * TX, ybase = ty * TY, zbase = tz * CZ;
    const int tid = threadIdx.x;
    const float* pn = phi + (long long)n * DIM * DIM * DIM;

    // ---- staging maps, hoisted ----
    int goff[5], loff[5];
#pragma unroll
    for (int it = 0; it < 5; ++it) {
        int idx = tid + it * 256; if (idx > NELEM - 1) idx = NELEM - 1;
        int ly = idx / HX, lx = idx - ly * HX;
        int iy = ybase + ly; if (iy > DIM - 1) iy = DIM - 1;
        int ix = xbase + lx; if (ix > DIM - 1) ix = DIM - 1;
        goff[it] = iy * DIM + ix;
        loff[it] = ly * LX + lx;
    }
    const bool st5 = (tid + 1024 < NELEM);   // guard 5th write: no dup-address conflicts

    float pf[5];
    auto pref = [&](int g) {                 // global -> VGPR, stays in flight
        int gz = zbase + g; if (gz > DIM - 1) gz = DIM - 1;
        const float* src = pn + gz * DIM * DIM;
#pragma unroll
        for (int it = 0; it < 5; ++it) pf[it] = src[goff[it]];
    };
    float* tf = &tile[0][0][0];
    auto commit = [&](int slot) {            // VGPR -> LDS
        float* t = tf + slot * (HY * LX);
#pragma unroll
        for (int it = 0; it < 4; ++it) t[loff[it]] = pf[it];
        if (st5) t[loff[4]] = pf[4];
    };

    const int row = tid >> 3;          // output y within tile (0..31)
    const int x0  = (tid & 7) * 4;     // output x within tile (0..28)

    auto read_slice = [&](int slot, Slice& s) {
#pragma unroll
        for (int dy = 0; dy < 3; ++dy) {
            const float* rp = &tile[slot][row + dy][x0];
            const float4 a = *(const float4*)rp;
            const float2 b = *(const float2*)(rp + 4);
            s.q[dy][0] = (v2f){a.x, a.z};
            s.q[dy][1] = (v2f){a.y, a.w};
            s.q[dy][2] = (v2f){a.z, b.x};
            s.q[dy][3] = (v2f){a.w, b.y};
            if (dy == 0) {
                s.mn[0] = a.x; s.mn[1] = a.y; s.mn[2] = a.z;
                s.mn[3] = a.w; s.mn[4] = b.x; s.mn[5] = b.y;
                s.mx[0] = a.x; s.mx[1] = a.y; s.mx[2] = a.z;
                s.mx[3] = a.w; s.mx[4] = b.x; s.mx[5] = b.y;
            } else {
                s.mn[0] = fminf(s.mn[0], a.x); s.mx[0] = fmaxf(s.mx[0], a.x);
                s.mn[1] = fminf(s.mn[1], a.y); s.mx[1] = fmaxf(s.mx[1], a.y);
                s.mn[2] = fminf(s.mn[2], a.z); s.mx[2] = fmaxf(s.mx[2], a.z);
                s.mn[3] = fminf(s.mn[3], a.w); s.mx[3] = fmaxf(s.mx[3], a.w);
                s.mn[4] = fminf(s.mn[4], b.x); s.mx[4] = fmaxf(s.mx[4], b.x);
                s.mn[5] = fminf(s.mn[5], b.y); s.mx[5] = fmaxf(s.mx[5], b.y);
            }
        }
    };

    double sp = 0.0, sc = 0.0;
    const float EPSF = 1e-8f;
    const int oy = ybase + row;

    bool vmask[4];
#pragma unroll
    for (int j = 0; j < 4; ++j)
        vmask[j] = (oy < ODIM) && (xbase + x0 + j < ODIM);

    auto compute = [&](const Slice& s0, const Slice& s1, const Slice& s2, int zo) {
        const int oz = zbase + zo;
        if (oz >= ODIM) return;              // block-uniform skip

        float colmn[6], colmx[6];
#pragma unroll
        for (int c = 0; c < 6; ++c) {
            colmn[c] = fminf(fminf(s0.mn[c], s1.mn[c]), s2.mn[c]);
            colmx[c] = fmaxf(fmaxf(s0.mx[c], s1.mx[c]), s2.mx[c]);
        }

        float fsp = 0.0f, fsc = 0.0f;
#pragma unroll
        for (int p = 0; p < 2; ++p) {
            // packed taps: tap(dx) = q[dx+p]; elem .x = voxel p, .y = voxel p+2
            v2f gx = 0.5f * (s2.q[1][p + 1] - s0.q[1][p + 1]);
            v2f gy = 0.5f * (s1.q[2][p + 1] - s1.q[0][p + 1]);
            v2f gz = 0.5f * (s1.q[1][p + 2] - s1.q[1][p]);

            v2f c2  = 2.0f * s1.q[1][p + 1];
            v2f hxx = s0.q[1][p + 1] - c2 + s2.q[1][p + 1];
            v2f hyy = s1.q[0][p + 1] - c2 + s1.q[2][p + 1];
            v2f hzz = s1.q[1][p] - c2 + s1.q[1][p + 2];

            v2f hxy = 0.25f * (s0.q[0][p + 1] - s0.q[2][p + 1]
                             - s2.q[0][p + 1] + s2.q[2][p + 1]);
            v2f hxz = 0.25f * (s0.q[1][p] - s0.q[1][p + 2]
                             - s2.q[1][p] + s2.q[1][p + 2]);
            v2f hyz = 0.25f * (s1.q[0][p] - s1.q[0][p + 2]
                             - s1.q[2][p] + s1.q[2][p + 2]);

            v2f gx2 = gx * gx, gy2 = gy * gy, gz2 = gz * gz;
            v2f mag2 = gx2 + gy2 + gz2 + EPSF;
            v2f mag  = (v2f){ sqrtf(mag2.x), sqrtf(mag2.y) };
            v2f mag3 = mag2 * mag;

            v2f cross = gx * gy * hxy + gx * gz * hxz + gy * gz * hyz;
            v2f inv3 = (v2f){ __builtin_amdgcn_rcpf(mag3.x + EPSF),
                              __builtin_amdgcn_rcpf(mag3.y + EPSF) };
            v2f inv1 = (v2f){ __builtin_amdgcn_rcpf(mag.x + EPSF),
                              __builtin_amdgcn_rcpf(mag.y + EPSF) };

            v2f mean_c = (gx2 * (hyy + hzz) + gy2 * (hxx + hzz) +
                          gz2 * (hxx + hyy) - 2.0f * cross) * inv3;
            v2f lap   = (hxx + hyy + hzz) * inv1;
            v2f quad  = (gx2 * hxx + gy2 * hyy + gz2 * hzz + 2.0f * cross) * inv3;
            v2f gauss = lap - quad;

            v2f disc = mean_c * mean_c - gauss;
            v2f sq = (v2f){ sqrtf(fabsf(disc.x) + EPSF),
                            sqrtf(fabsf(disc.y) + EPSF) };
            v2f k1 = mean_c + sq;
            v2f t  = 2.0f * k1;              // k1 / (0.5+1e-8) == 2*k1 in f32
            v2f pen2 = t * t - 1.0f;

#pragma unroll
            for (int e = 0; e < 2; ++e) {
                const int j = p + 2 * e;
                float pen = fmaxf(e ? pen2.y : pen2.x, 0.0f);
                float mn = fminf(fminf(colmn[j], colmn[j + 1]), colmn[j + 2]);
                float mx = fmaxf(fmaxf(colmx[j], colmx[j + 1]), colmx[j + 2]);
                if (vmask[j] && (mn * mx < 0.0f)) {
                    fsp += pen;
                    fsc += 1.0f;
                }
            }
        }
        sp += (double)fsp;
        sc += (double)fsc;
    };

    Slice s0, s1, s2;

    // ---- prologue ----
    pref(0); commit(0);
    pref(1); commit(1);
    pref(2);
    __syncthreads();
    read_slice(0, s0);
    read_slice(1, s1);

    // ---- 7 pipelined phases ----
    commit(2); pref(3); __syncthreads(); read_slice(2, s2); compute(s0, s1, s2, 0);
    commit(0); pref(4); __syncthreads(); read_slice(0, s0); compute(s1, s2, s0, 1);
    commit(1); pref(5); __syncthreads(); read_slice(1, s1); compute(s2, s0, s1, 2);
    commit(2); pref(6); __syncthreads(); read_slice(2, s2); compute(s0, s1, s2, 3);
    commit(0); pref(7); __syncthreads(); read_slice(0, s0); compute(s1, s2, s0, 4);
    commit(1); pref(8); __syncthreads(); read_slice(1, s1); compute(s2, s0, s1, 5);
    commit(2);          __syncthreads(); read_slice(2, s2); compute(s0, s1, s2, 6);

    // ---- reduction ----
#pragma unroll
    for (int off = 32; off > 0; off >>= 1) {
        sp += __shfl_down(sp, off, 64);
        sc += __shfl_down(sc, off, 64);
    }

    __shared__ double lsp[4], lsc[4];
    const int wave = tid >> 6, lane = tid & 63;
    if (lane == 0) { lsp[wave] = sp; lsc[wave] = sc; }
    __syncthreads();
    if (tid == 0) {
        double tp = lsp[0] + lsp[1] + lsp[2] + lsp[3];
        double tc = lsc[0] + lsc[1] + lsc[2] + lsc[3];
        if (use_partials) {
            acc[2 * blockIdx.x]     = tp;
            acc[2 * blockIdx.x + 1] = tc;
        } else {
            atomicAdd(&acc[0], tp);
            atomicAdd(&acc[1], tc);
        }
    }
}

__global__ __launch_bounds__(256) void curv_reduce(const double* __restrict__ part,
                                                   int nblocks, int use_partials,
                                                   float* __restrict__ out) {
    double sp = 0.0, sc = 0.0;
    if (use_partials) {
        for (int i = threadIdx.x; i < nblocks; i += 256) {
            sp += part[2 * i];
            sc += part[2 * i + 1];
        }
    } else if (threadIdx.x == 0) {
        sp = part[0]; sc = part[1];
    }
#pragma unroll
    for (int off = 32; off > 0; off >>= 1) {
        sp += __shfl_down(sp, off, 64);
        sc += __shfl_down(sc, off, 64);
    }
    __shared__ double lsp[4], lsc[4];
    const int wave = threadIdx.x >> 6, lane = threadIdx.x & 63;
    if (lane == 0) { lsp[wave] = sp; lsc[wave] = sc; }
    __syncthreads();
    if (threadIdx.x == 0) {
        double tp = lsp[0] + lsp[1] + lsp[2] + lsp[3];
        double tc = lsc[0] + lsc[1] + lsc[2] + lsc[3];
        out[0] = (float)(tp / (tc + 1e-8));
    }
}

extern "C" void kernel_launch(void* const* d_in, const int* in_sizes, int n_in,
                              void* d_out, int out_size, void* d_ws, size_t ws_size,
                              hipStream_t stream) {
    const float* phi = (const float*)d_in[0];
    float* out = (float*)d_out;
    double* acc = (double*)d_ws;

    const int use_partials = (ws_size >= (size_t)(2 * NBLOCKS) * sizeof(double)) ? 1 : 0;
    if (!use_partials) {
        hipMemsetAsync(d_ws, 0, 2 * sizeof(double), stream);
    }

    curv_main<<<NBLOCKS, 256, 0, stream>>>(phi, acc, use_partials);
    curv_reduce<<<1, 256, 0, stream>>>(acc, NBLOCKS, use_partials, out);
}

// Round 6
// 117.342 us; speedup vs baseline: 1.4133x; 1.4133x over previous
//
#include <hip/hip_runtime.h>

// CurvatureLoss3D — 2.5D LDS-tiled, register z-sliding, software-pipelined
// staging. R6: R4 scalar-slice structure (60 VGPR, no spill) + grid 2016
// (98% lockstep-round fill vs 2304's 75%) + guarded 5th staging write (no
// dup-address LDS conflicts) + rsqrt-based inverse magnitudes.

constexpr int DIM  = 192;
constexpr int ODIM = 190;
constexpr int TX = 32, TY = 32, CZ = 7;
constexpr int NTX = 6, NTY = 6, NTZ = 28;   // 28*7 = 196 >= 190
constexpr int HX = 34, HY = 34;
constexpr int LX = 36;                      // padded LDS row stride
constexpr int NELEM = HX * HY;              // 1156
constexpr int NBLOCKS = 2 * NTZ * NTY * NTX;  // 2016

struct Slice {
    float v[3][6];          // rows y..y+2, cols x0..x0+5 of one z-plane
    float mn[6], mx[6];     // per-column min/max over the 3 rows
};

__global__ __launch_bounds__(256, 4) void curv_main(const float* __restrict__ phi,
                                                    double* __restrict__ acc,
                                                    int use_partials) {
    __shared__ __align__(16) float tile[3][HY][LX];

    int bx = blockIdx.x;
    const int tx = bx % NTX; bx /= NTX;
    const int ty = bx % NTY; bx /= NTY;
    const int tz = bx % NTZ; bx /= NTZ;
    const int n  = bx;

    const int xbase = tx * TX, ybase = ty * TY, zbase = tz * CZ;
    const int tid = threadIdx.x;
    const float* pn = phi + (long long)n * DIM * DIM * DIM;

    // ---- staging maps, hoisted ----
    int goff[5], loff[5];
#pragma unroll
    for (int it = 0; it < 5; ++it) {
        int idx = tid + it * 256; if (idx > NELEM - 1) idx = NELEM - 1;
        int ly = idx / HX, lx = idx - ly * HX;
        int iy = ybase + ly; if (iy > DIM - 1) iy = DIM - 1;
        int ix = xbase + lx; if (ix > DIM - 1) ix = DIM - 1;
        goff[it] = iy * DIM + ix;
        loff[it] = ly * LX + lx;
    }
    const bool st5 = (tid + 1024 < NELEM);   // guard 5th write (no dup addresses)

    float pf[5];
    auto pref = [&](int g) {                 // global -> VGPR, stays in flight
        int gz = zbase + g; if (gz > DIM - 1) gz = DIM - 1;
        const float* src = pn + gz * DIM * DIM;
#pragma unroll
        for (int it = 0; it < 5; ++it) pf[it] = src[goff[it]];
    };
    float* tf = &tile[0][0][0];
    auto commit = [&](int slot) {            // VGPR -> LDS
        float* t = tf + slot * (HY * LX);
#pragma unroll
        for (int it = 0; it < 4; ++it) t[loff[it]] = pf[it];
        if (st5) t[loff[4]] = pf[4];
    };

    const int row = tid >> 3;          // output y within tile (0..31)
    const int x0  = (tid & 7) * 4;     // output x within tile (0..28)

    auto read_slice = [&](int slot, Slice& s) {
#pragma unroll
        for (int dy = 0; dy < 3; ++dy) {
            const float* rp = &tile[slot][row + dy][x0];
            const float4 a = *(const float4*)rp;
            const float2 b = *(const float2*)(rp + 4);
            s.v[dy][0] = a.x; s.v[dy][1] = a.y; s.v[dy][2] = a.z;
            s.v[dy][3] = a.w; s.v[dy][4] = b.x; s.v[dy][5] = b.y;
        }
#pragma unroll
        for (int c = 0; c < 6; ++c) {
            s.mn[c] = fminf(fminf(s.v[0][c], s.v[1][c]), s.v[2][c]);
            s.mx[c] = fmaxf(fmaxf(s.v[0][c], s.v[1][c]), s.v[2][c]);
        }
    };

    double sp = 0.0, sc = 0.0;
    const float EPSF = 1e-8f;
    const int oy = ybase + row;

    bool vmask[4];
#pragma unroll
    for (int j = 0; j < 4; ++j)
        vmask[j] = (oy < ODIM) && (xbase + x0 + j < ODIM);

    auto compute = [&](const Slice& s0, const Slice& s1, const Slice& s2, int zo) {
        const int oz = zbase + zo;
        if (oz >= ODIM) return;              // block-uniform skip

        float colmn[6], colmx[6];
#pragma unroll
        for (int c = 0; c < 6; ++c) {
            colmn[c] = fminf(fminf(s0.mn[c], s1.mn[c]), s2.mn[c]);
            colmx[c] = fmaxf(fmaxf(s0.mx[c], s1.mx[c]), s2.mx[c]);
        }

        float fsp = 0.0f, fsc = 0.0f;
#pragma unroll
        for (int j = 0; j < 4; ++j) {
            float gx = 0.5f * (s2.v[1][j + 1] - s0.v[1][j + 1]);
            float gy = 0.5f * (s1.v[2][j + 1] - s1.v[0][j + 1]);
            float gz = 0.5f * (s1.v[1][j + 2] - s1.v[1][j]);

            float c2  = 2.0f * s1.v[1][j + 1];
            float hxx = s0.v[1][j + 1] - c2 + s2.v[1][j + 1];
            float hyy = s1.v[0][j + 1] - c2 + s1.v[2][j + 1];
            float hzz = s1.v[1][j] - c2 + s1.v[1][j + 2];

            float hxy = 0.25f * (s0.v[0][j + 1] - s0.v[2][j + 1]
                               - s2.v[0][j + 1] + s2.v[2][j + 1]);
            float hxz = 0.25f * (s0.v[1][j] - s0.v[1][j + 2]
                               - s2.v[1][j] + s2.v[1][j + 2]);
            float hyz = 0.25f * (s1.v[0][j] - s1.v[0][j + 2]
                               - s1.v[2][j] + s1.v[2][j + 2]);

            float gx2 = gx * gx, gy2 = gy * gy, gz2 = gz * gz;
            float mag2 = gx2 + gy2 + gz2 + EPSF;

            // inv_mag = 1/sqrt(mag2); inv3 = inv_mag^3 (eps already in mag2)
            float inv1 = __builtin_amdgcn_rsqf(mag2);
            float inv3 = inv1 * inv1 * inv1;

            float cross = gx * gy * hxy + gx * gz * hxz + gy * gz * hyz;

            float mean_c = (gx2 * (hyy + hzz) + gy2 * (hxx + hzz) +
                            gz2 * (hxx + hyy) - 2.0f * cross) * inv3;
            float lap   = (hxx + hyy + hzz) * inv1;
            float quad  = (gx2 * hxx + gy2 * hyy + gz2 * hzz + 2.0f * cross) * inv3;
            float gauss = lap - quad;

            float k1  = mean_c + sqrtf(fabsf(mean_c * mean_c - gauss) + EPSF);
            float t   = 2.0f * k1;           // k1 / (0.5 + 1e-8) == 2*k1 in f32
            float pen = fmaxf(t * t - 1.0f, 0.0f);

            float mn = fminf(fminf(colmn[j], colmn[j + 1]), colmn[j + 2]);
            float mx = fmaxf(fmaxf(colmx[j], colmx[j + 1]), colmx[j + 2]);

            if (vmask[j] && (mn * mx < 0.0f)) {
                fsp += pen;
                fsc += 1.0f;
            }
        }
        sp += (double)fsp;
        sc += (double)fsc;
    };

    Slice s0, s1, s2;

    // ---- prologue ----
    pref(0); commit(0);
    pref(1); commit(1);
    pref(2);
    __syncthreads();
    read_slice(0, s0);
    read_slice(1, s1);

    // ---- 7 pipelined phases ----
    commit(2); pref(3); __syncthreads(); read_slice(2, s2); compute(s0, s1, s2, 0);
    commit(0); pref(4); __syncthreads(); read_slice(0, s0); compute(s1, s2, s0, 1);
    commit(1); pref(5); __syncthreads(); read_slice(1, s1); compute(s2, s0, s1, 2);
    commit(2); pref(6); __syncthreads(); read_slice(2, s2); compute(s0, s1, s2, 3);
    commit(0); pref(7); __syncthreads(); read_slice(0, s0); compute(s1, s2, s0, 4);
    commit(1); pref(8); __syncthreads(); read_slice(1, s1); compute(s2, s0, s1, 5);
    commit(2);          __syncthreads(); read_slice(2, s2); compute(s0, s1, s2, 6);

    // ---- reduction ----
#pragma unroll
    for (int off = 32; off > 0; off >>= 1) {
        sp += __shfl_down(sp, off, 64);
        sc += __shfl_down(sc, off, 64);
    }

    __shared__ double lsp[4], lsc[4];
    const int wave = tid >> 6, lane = tid & 63;
    if (lane == 0) { lsp[wave] = sp; lsc[wave] = sc; }
    __syncthreads();
    if (tid == 0) {
        double tp = lsp[0] + lsp[1] + lsp[2] + lsp[3];
        double tc = lsc[0] + lsc[1] + lsc[2] + lsc[3];
        if (use_partials) {
            acc[2 * blockIdx.x]     = tp;
            acc[2 * blockIdx.x + 1] = tc;
        } else {
            atomicAdd(&acc[0], tp);
            atomicAdd(&acc[1], tc);
        }
    }
}

__global__ __launch_bounds__(256) void curv_reduce(const double* __restrict__ part,
                                                   int nblocks, int use_partials,
                                                   float* __restrict__ out) {
    double sp = 0.0, sc = 0.0;
    if (use_partials) {
        for (int i = threadIdx.x; i < nblocks; i += 256) {
            sp += part[2 * i];
            sc += part[2 * i + 1];
        }
    } else if (threadIdx.x == 0) {
        sp = part[0]; sc = part[1];
    }
#pragma unroll
    for (int off = 32; off > 0; off >>= 1) {
        sp += __shfl_down(sp, off, 64);
        sc += __shfl_down(sc, off, 64);
    }
    __shared__ double lsp[4], lsc[4];
    const int wave = threadIdx.x >> 6, lane = threadIdx.x & 63;
    if (lane == 0) { lsp[wave] = sp; lsc[wave] = sc; }
    __syncthreads();
    if (threadIdx.x == 0) {
        double tp = lsp[0] + lsp[1] + lsp[2] + lsp[3];
        double tc = lsc[0] + lsc[1] + lsc[2] + lsc[3];
        out[0] = (float)(tp / (tc + 1e-8));
    }
}

extern "C" void kernel_launch(void* const* d_in, const int* in_sizes, int n_in,
                              void* d_out, int out_size, void* d_ws, size_t ws_size,
                              hipStream_t stream) {
    const float* phi = (const float*)d_in[0];
    float* out = (float*)d_out;
    double* acc = (double*)d_ws;

    const int use_partials = (ws_size >= (size_t)(2 * NBLOCKS) * sizeof(double)) ? 1 : 0;
    if (!use_partials) {
        hipMemsetAsync(d_ws, 0, 2 * sizeof(double), stream);
    }

    curv_main<<<NBLOCKS, 256, 0, stream>>>(phi, acc, use_partials);
    curv_reduce<<<1, 256, 0, stream>>>(acc, NBLOCKS, use_partials, out);
}

// Round 7
// 112.878 us; speedup vs baseline: 1.4692x; 1.0395x over previous
//
#include <hip/hip_runtime.h>

// CurvatureLoss3D — 2.5D LDS-tiled, register z-sliding, software-pipelined
// staging, PACKED-FP32 curvature math (v_pk_fma_f32 via float2 ext-vectors).
//
// R7 = R5's packing (verified exact, absmax 0.0) + R6's fixes (grid 2016,
// guarded 5th staging write, rsqrt inverses) + the register-budget fix:
// __launch_bounds__(256,3) caps VGPR at ~170 (R5's (256,4) capped at 128 and
// spilled 121 MB of scratch). Packed slices need ~155 live VGPRs.
//
// Packing trick: thread owns 4 x-adjacent voxels paired stride-2 (pair p =
// voxels {p, p+2}); with q[k] = (r[k], r[k+2]) the packed stencil tap at dx
// for pair p is exactly q[dx+p] — no repacking movs inside the math.

typedef float v2f __attribute__((ext_vector_type(2)));

constexpr int DIM  = 192;
constexpr int ODIM = 190;
constexpr int TX = 32, TY = 32, CZ = 7;
constexpr int NTX = 6, NTY = 6, NTZ = 28;   // 28*7 = 196 >= 190
constexpr int HX = 34, HY = 34;
constexpr int LX = 36;                      // padded LDS row stride
constexpr int NELEM = HX * HY;              // 1156
constexpr int NBLOCKS = 2 * NTZ * NTY * NTX;  // 2016

struct Slice {
    v2f   q[3][4];          // rows y..y+2; q[dy][k] = (r[k], r[k+2])
    float mn[6], mx[6];     // per-column min/max over the 3 rows
};

__global__ __launch_bounds__(256, 3) void curv_main(const float* __restrict__ phi,
                                                    double* __restrict__ acc,
                                                    int use_partials) {
    __shared__ __align__(16) float tile[3][HY][LX];

    int bx = blockIdx.x;
    const int tx = bx % NTX; bx /= NTX;
    const int ty = bx % NTY; bx /= NTY;
    const int tz = bx % NTZ; bx /= NTZ;
    const int n  = bx;

    const int xbase = tx * TX, ybase = ty * TY, zbase = tz * CZ;
    const int tid = threadIdx.x;
    const float* pn = phi + (long long)n * DIM * DIM * DIM;

    // ---- staging maps, hoisted ----
    int goff[5], loff[5];
#pragma unroll
    for (int it = 0; it < 5; ++it) {
        int idx = tid + it * 256; if (idx > NELEM - 1) idx = NELEM - 1;
        int ly = idx / HX, lx = idx - ly * HX;
        int iy = ybase + ly; if (iy > DIM - 1) iy = DIM - 1;
        int ix = xbase + lx; if (ix > DIM - 1) ix = DIM - 1;
        goff[it] = iy * DIM + ix;
        loff[it] = ly * LX + lx;
    }
    const bool st5 = (tid + 1024 < NELEM);   // guard 5th write

    float pf[5];
    auto pref = [&](int g) {                 // global -> VGPR, stays in flight
        int gz = zbase + g; if (gz > DIM - 1) gz = DIM - 1;
        const float* src = pn + gz * DIM * DIM;
#pragma unroll
        for (int it = 0; it < 5; ++it) pf[it] = src[goff[it]];
    };
    float* tf = &tile[0][0][0];
    auto commit = [&](int slot) {            // VGPR -> LDS
        float* t = tf + slot * (HY * LX);
#pragma unroll
        for (int it = 0; it < 4; ++it) t[loff[it]] = pf[it];
        if (st5) t[loff[4]] = pf[4];
    };

    const int row = tid >> 3;          // output y within tile (0..31)
    const int x0  = (tid & 7) * 4;     // output x within tile (0..28)

    auto read_slice = [&](int slot, Slice& s) {
#pragma unroll
        for (int dy = 0; dy < 3; ++dy) {
            const float* rp = &tile[slot][row + dy][x0];
            const float4 a = *(const float4*)rp;
            const float2 b = *(const float2*)(rp + 4);
            s.q[dy][0] = (v2f){a.x, a.z};
            s.q[dy][1] = (v2f){a.y, a.w};
            s.q[dy][2] = (v2f){a.z, b.x};
            s.q[dy][3] = (v2f){a.w, b.y};
            if (dy == 0) {
                s.mn[0] = a.x; s.mn[1] = a.y; s.mn[2] = a.z;
                s.mn[3] = a.w; s.mn[4] = b.x; s.mn[5] = b.y;
                s.mx[0] = a.x; s.mx[1] = a.y; s.mx[2] = a.z;
                s.mx[3] = a.w; s.mx[4] = b.x; s.mx[5] = b.y;
            } else {
                s.mn[0] = fminf(s.mn[0], a.x); s.mx[0] = fmaxf(s.mx[0], a.x);
                s.mn[1] = fminf(s.mn[1], a.y); s.mx[1] = fmaxf(s.mx[1], a.y);
                s.mn[2] = fminf(s.mn[2], a.z); s.mx[2] = fmaxf(s.mx[2], a.z);
                s.mn[3] = fminf(s.mn[3], a.w); s.mx[3] = fmaxf(s.mx[3], a.w);
                s.mn[4] = fminf(s.mn[4], b.x); s.mx[4] = fmaxf(s.mx[4], b.x);
                s.mn[5] = fminf(s.mn[5], b.y); s.mx[5] = fmaxf(s.mx[5], b.y);
            }
        }
    };

    double sp = 0.0, sc = 0.0;
    const float EPSF = 1e-8f;
    const int oy = ybase + row;

    bool vmask[4];
#pragma unroll
    for (int j = 0; j < 4; ++j)
        vmask[j] = (oy < ODIM) && (xbase + x0 + j < ODIM);

    auto compute = [&](const Slice& s0, const Slice& s1, const Slice& s2, int zo) {
        const int oz = zbase + zo;
        if (oz >= ODIM) return;              // block-uniform skip

        float colmn[6], colmx[6];
#pragma unroll
        for (int c = 0; c < 6; ++c) {
            colmn[c] = fminf(fminf(s0.mn[c], s1.mn[c]), s2.mn[c]);
            colmx[c] = fmaxf(fmaxf(s0.mx[c], s1.mx[c]), s2.mx[c]);
        }

        float fsp = 0.0f, fsc = 0.0f;
#pragma unroll
        for (int p = 0; p < 2; ++p) {
            // packed taps: tap(dx) = q[dx+p]; elem .x = voxel p, .y = voxel p+2
            v2f gx = 0.5f * (s2.q[1][p + 1] - s0.q[1][p + 1]);
            v2f gy = 0.5f * (s1.q[2][p + 1] - s1.q[0][p + 1]);
            v2f gz = 0.5f * (s1.q[1][p + 2] - s1.q[1][p]);

            v2f c2  = 2.0f * s1.q[1][p + 1];
            v2f hxx = s0.q[1][p + 1] - c2 + s2.q[1][p + 1];
            v2f hyy = s1.q[0][p + 1] - c2 + s1.q[2][p + 1];
            v2f hzz = s1.q[1][p] - c2 + s1.q[1][p + 2];

            v2f hxy = 0.25f * (s0.q[0][p + 1] - s0.q[2][p + 1]
                             - s2.q[0][p + 1] + s2.q[2][p + 1]);
            v2f hxz = 0.25f * (s0.q[1][p] - s0.q[1][p + 2]
                             - s2.q[1][p] + s2.q[1][p + 2]);
            v2f hyz = 0.25f * (s1.q[0][p] - s1.q[0][p + 2]
                             - s1.q[2][p] + s1.q[2][p + 2]);

            v2f gx2 = gx * gx, gy2 = gy * gy, gz2 = gz * gz;
            v2f mag2 = gx2 + gy2 + gz2 + EPSF;

            v2f inv1 = (v2f){ __builtin_amdgcn_rsqf(mag2.x),
                              __builtin_amdgcn_rsqf(mag2.y) };
            v2f inv3 = inv1 * inv1 * inv1;

            v2f cross = gx * gy * hxy + gx * gz * hxz + gy * gz * hyz;

            v2f mean_c = (gx2 * (hyy + hzz) + gy2 * (hxx + hzz) +
                          gz2 * (hxx + hyy) - 2.0f * cross) * inv3;
            v2f lap   = (hxx + hyy + hzz) * inv1;
            v2f quad  = (gx2 * hxx + gy2 * hyy + gz2 * hzz + 2.0f * cross) * inv3;
            v2f gauss = lap - quad;

            v2f disc = mean_c * mean_c - gauss;
            v2f sq = (v2f){ sqrtf(fabsf(disc.x) + EPSF),
                            sqrtf(fabsf(disc.y) + EPSF) };
            v2f k1 = mean_c + sq;
            v2f t  = 2.0f * k1;              // k1 / (0.5+1e-8) == 2*k1 in f32
            v2f pen2 = t * t - 1.0f;

#pragma unroll
            for (int e = 0; e < 2; ++e) {
                const int j = p + 2 * e;
                float pen = fmaxf(e ? pen2.y : pen2.x, 0.0f);
                float mn = fminf(fminf(colmn[j], colmn[j + 1]), colmn[j + 2]);
                float mx = fmaxf(fmaxf(colmx[j], colmx[j + 1]), colmx[j + 2]);
                if (vmask[j] && (mn * mx < 0.0f)) {
                    fsp += pen;
                    fsc += 1.0f;
                }
            }
        }
        sp += (double)fsp;
        sc += (double)fsc;
    };

    Slice s0, s1, s2;

    // ---- prologue ----
    pref(0); commit(0);
    pref(1); commit(1);
    pref(2);
    __syncthreads();
    read_slice(0, s0);
    read_slice(1, s1);

    // ---- 7 pipelined phases ----
    commit(2); pref(3); __syncthreads(); read_slice(2, s2); compute(s0, s1, s2, 0);
    commit(0); pref(4); __syncthreads(); read_slice(0, s0); compute(s1, s2, s0, 1);
    commit(1); pref(5); __syncthreads(); read_slice(1, s1); compute(s2, s0, s1, 2);
    commit(2); pref(6); __syncthreads(); read_slice(2, s2); compute(s0, s1, s2, 3);
    commit(0); pref(7); __syncthreads(); read_slice(0, s0); compute(s1, s2, s0, 4);
    commit(1); pref(8); __syncthreads(); read_slice(1, s1); compute(s2, s0, s1, 5);
    commit(2);          __syncthreads(); read_slice(2, s2); compute(s0, s1, s2, 6);

    // ---- reduction ----
#pragma unroll
    for (int off = 32; off > 0; off >>= 1) {
        sp += __shfl_down(sp, off, 64);
        sc += __shfl_down(sc, off, 64);
    }

    __shared__ double lsp[4], lsc[4];
    const int wave = tid >> 6, lane = tid & 63;
    if (lane == 0) { lsp[wave] = sp; lsc[wave] = sc; }
    __syncthreads();
    if (tid == 0) {
        double tp = lsp[0] + lsp[1] + lsp[2] + lsp[3];
        double tc = lsc[0] + lsc[1] + lsc[2] + lsc[3];
        if (use_partials) {
            acc[2 * blockIdx.x]     = tp;
            acc[2 * blockIdx.x + 1] = tc;
        } else {
            atomicAdd(&acc[0], tp);
            atomicAdd(&acc[1], tc);
        }
    }
}

__global__ __launch_bounds__(256) void curv_reduce(const double* __restrict__ part,
                                                   int nblocks, int use_partials,
                                                   float* __restrict__ out) {
    double sp = 0.0, sc = 0.0;
    if (use_partials) {
        for (int i = threadIdx.x; i < nblocks; i += 256) {
            sp += part[2 * i];
            sc += part[2 * i + 1];
        }
    } else if (threadIdx.x == 0) {
        sp = part[0]; sc = part[1];
    }
#pragma unroll
    for (int off = 32; off > 0; off >>= 1) {
        sp += __shfl_down(sp, off, 64);
        sc += __shfl_down(sc, off, 64);
    }
    __shared__ double lsp[4], lsc[4];
    const int wave = threadIdx.x >> 6, lane = threadIdx.x & 63;
    if (lane == 0) { lsp[wave] = sp; lsc[wave] = sc; }
    __syncthreads();
    if (threadIdx.x == 0) {
        double tp = lsp[0] + lsp[1] + lsp[2] + lsp[3];
        double tc = lsc[0] + lsc[1] + lsc[2] + lsc[3];
        out[0] = (float)(tp / (tc + 1e-8));
    }
}

extern "C" void kernel_launch(void* const* d_in, const int* in_sizes, int n_in,
                              void* d_out, int out_size, void* d_ws, size_t ws_size,
                              hipStream_t stream) {
    const float* phi = (const float*)d_in[0];
    float* out = (float*)d_out;
    double* acc = (double*)d_ws;

    const int use_partials = (ws_size >= (size_t)(2 * NBLOCKS) * sizeof(double)) ? 1 : 0;
    if (!use_partials) {
        hipMemsetAsync(d_ws, 0, 2 * sizeof(double), stream);
    }

    curv_main<<<NBLOCKS, 256, 0, stream>>>(phi, acc, use_partials);
    curv_reduce<<<1, 256, 0, stream>>>(acc, NBLOCKS, use_partials, out);
}

// Round 8
// 110.900 us; speedup vs baseline: 1.4955x; 1.0178x over previous
//
#include <hip/hip_runtime.h>

// CurvatureLoss3D — R8: no-LDS register-sliding stencil. Each thread owns a
// 1(y) x 4(x) voxel strip and slides over CZ=10 z-planes, holding a packed
// 3(z)x3(y)x6(x) window in registers. The new plane's 3 rows x 6 floats are
// read straight from global (float4+float2, aligned); L1/L2 serve the
// y/x-halo overlap that LDS used to de-duplicate. No barriers, no ds ops,
// no LDS bank conflicts, no lockstep rounds — loads of plane z+3 stay in
// flight across compute of plane z (per-wave pipeline, no workgroup sync).
//
// Packed-FP32 math (v_pk_fma_f32 via float2 ext-vectors), pair-stride-2
// trick: q[k] = (r[k], r[k+2]) makes the packed tap for pair p at dx exactly
// q[dx+p]. Verified exact (absmax 0.0 in R5/R7).
//
// Boundary handling (no LDS clamp): float4 col c4 = xbase+x0 <= 188 always
// in-bounds; float2 col clamped to 190 — wrong taps feed only voxels with
// ox >= 190 (masked invalid). Clamped y/z rows likewise feed only masked
// voxels. CZ*NTZ = 190 exactly: no z tail.

typedef float v2f __attribute__((ext_vector_type(2)));

constexpr int DIM  = 192;
constexpr int ODIM = 190;
constexpr int TX = 32, TY = 32, CZ = 10;
constexpr int NTX = 6, NTY = 6, NTZ = 19;     // 19*10 = 190 exactly
constexpr int PLANE = DIM * DIM;
constexpr int NBLOCKS = 2 * NTZ * NTY * NTX;  // 1368

struct Slice {
    v2f   q[3][4];          // rows y..y+2; q[dy][k] = (r[k], r[k+2])
    float mn[6], mx[6];     // per-column min/max over the 3 rows
};

__global__ __launch_bounds__(256, 3) void curv_main(const float* __restrict__ phi,
                                                    double* __restrict__ acc,
                                                    int use_partials) {
    int bx = blockIdx.x;
    const int tx = bx % NTX; bx /= NTX;
    const int ty = bx % NTY; bx /= NTY;
    const int tz = bx % NTZ; bx /= NTZ;
    const int n  = bx;

    const int xbase = tx * TX, ybase = ty * TY, zbase = tz * CZ;
    const int tid = threadIdx.x;
    const int row = tid >> 3;          // output y within tile (0..31)
    const int x0  = (tid & 7) * 4;     // output x within tile (0..28)
    const float* pn = phi + (long long)n * DIM * PLANE;

    // hoisted addresses
    const int c4 = xbase + x0;                       // <= 188: float4 in-bounds
    int c2t = c4 + 4; if (c2t > DIM - 2) c2t = DIM - 2;   // clamp: cols <= 191
    const int c2 = c2t;
    int yoff[3];
#pragma unroll
    for (int dy = 0; dy < 3; ++dy) {
        int iy = ybase + row + dy; if (iy > DIM - 1) iy = DIM - 1;
        yoff[dy] = iy * DIM;
    }

    float4 t4[3]; float2 t2[3];
    auto pref = [&](int g) {            // global -> tmp regs, stays in flight
        int gz = zbase + g; if (gz > DIM - 1) gz = DIM - 1;
        const float* base = pn + gz * PLANE;
#pragma unroll
        for (int dy = 0; dy < 3; ++dy) {
            t4[dy] = *(const float4*)(base + yoff[dy] + c4);
            t2[dy] = *(const float2*)(base + yoff[dy] + c2);
        }
    };

    auto unpack = [&](Slice& s) {       // tmp regs -> packed slice (+min/max)
#pragma unroll
        for (int dy = 0; dy < 3; ++dy) {
            const float4 a = t4[dy]; const float2 b = t2[dy];
            s.q[dy][0] = (v2f){a.x, a.z};
            s.q[dy][1] = (v2f){a.y, a.w};
            s.q[dy][2] = (v2f){a.z, b.x};
            s.q[dy][3] = (v2f){a.w, b.y};
            if (dy == 0) {
                s.mn[0] = a.x; s.mn[1] = a.y; s.mn[2] = a.z;
                s.mn[3] = a.w; s.mn[4] = b.x; s.mn[5] = b.y;
                s.mx[0] = a.x; s.mx[1] = a.y; s.mx[2] = a.z;
                s.mx[3] = a.w; s.mx[4] = b.x; s.mx[5] = b.y;
            } else {
                s.mn[0] = fminf(s.mn[0], a.x); s.mx[0] = fmaxf(s.mx[0], a.x);
                s.mn[1] = fminf(s.mn[1], a.y); s.mx[1] = fmaxf(s.mx[1], a.y);
                s.mn[2] = fminf(s.mn[2], a.z); s.mx[2] = fmaxf(s.mx[2], a.z);
                s.mn[3] = fminf(s.mn[3], a.w); s.mx[3] = fmaxf(s.mx[3], a.w);
                s.mn[4] = fminf(s.mn[4], b.x); s.mx[4] = fmaxf(s.mx[4], b.x);
                s.mn[5] = fminf(s.mn[5], b.y); s.mx[5] = fmaxf(s.mx[5], b.y);
            }
        }
    };

    double sp = 0.0, sc = 0.0;
    const float EPSF = 1e-8f;
    const int oy = ybase + row;

    bool vmask[4];
#pragma unroll
    for (int j = 0; j < 4; ++j)
        vmask[j] = (oy < ODIM) && (xbase + x0 + j < ODIM);

    auto compute = [&](const Slice& s0, const Slice& s1, const Slice& s2, int zo) {
        const int oz = zbase + zo;
        if (oz >= ODIM) return;              // never taken (19*10=190); cheap guard

        float colmn[6], colmx[6];
#pragma unroll
        for (int c = 0; c < 6; ++c) {
            colmn[c] = fminf(fminf(s0.mn[c], s1.mn[c]), s2.mn[c]);
            colmx[c] = fmaxf(fmaxf(s0.mx[c], s1.mx[c]), s2.mx[c]);
        }

        float fsp = 0.0f, fsc = 0.0f;
#pragma unroll
        for (int p = 0; p < 2; ++p) {
            v2f gx = 0.5f * (s2.q[1][p + 1] - s0.q[1][p + 1]);
            v2f gy = 0.5f * (s1.q[2][p + 1] - s1.q[0][p + 1]);
            v2f gz = 0.5f * (s1.q[1][p + 2] - s1.q[1][p]);

            v2f c2v = 2.0f * s1.q[1][p + 1];
            v2f hxx = s0.q[1][p + 1] - c2v + s2.q[1][p + 1];
            v2f hyy = s1.q[0][p + 1] - c2v + s1.q[2][p + 1];
            v2f hzz = s1.q[1][p] - c2v + s1.q[1][p + 2];

            v2f hxy = 0.25f * (s0.q[0][p + 1] - s0.q[2][p + 1]
                             - s2.q[0][p + 1] + s2.q[2][p + 1]);
            v2f hxz = 0.25f * (s0.q[1][p] - s0.q[1][p + 2]
                             - s2.q[1][p] + s2.q[1][p + 2]);
            v2f hyz = 0.25f * (s1.q[0][p] - s1.q[0][p + 2]
                             - s1.q[2][p] + s1.q[2][p + 2]);

            v2f gx2 = gx * gx, gy2 = gy * gy, gz2 = gz * gz;
            v2f mag2 = gx2 + gy2 + gz2 + EPSF;

            v2f inv1 = (v2f){ __builtin_amdgcn_rsqf(mag2.x),
                              __builtin_amdgcn_rsqf(mag2.y) };
            v2f inv3 = inv1 * inv1 * inv1;

            v2f cross = gx * gy * hxy + gx * gz * hxz + gy * gz * hyz;

            v2f mean_c = (gx2 * (hyy + hzz) + gy2 * (hxx + hzz) +
                          gz2 * (hxx + hyy) - 2.0f * cross) * inv3;
            v2f lap   = (hxx + hyy + hzz) * inv1;
            v2f quad  = (gx2 * hxx + gy2 * hyy + gz2 * hzz + 2.0f * cross) * inv3;
            v2f gauss = lap - quad;

            v2f disc = mean_c * mean_c - gauss;
            v2f sq = (v2f){ sqrtf(fabsf(disc.x) + EPSF),
                            sqrtf(fabsf(disc.y) + EPSF) };
            v2f k1 = mean_c + sq;
            v2f t  = 2.0f * k1;              // k1 / (0.5+1e-8) == 2*k1 in f32
            v2f pen2 = t * t - 1.0f;

#pragma unroll
            for (int e = 0; e < 2; ++e) {
                const int j = p + 2 * e;
                float pen = fmaxf(e ? pen2.y : pen2.x, 0.0f);
                float mn = fminf(fminf(colmn[j], colmn[j + 1]), colmn[j + 2]);
                float mx = fmaxf(fmaxf(colmx[j], colmx[j + 1]), colmx[j + 2]);
                if (vmask[j] && (mn * mx < 0.0f)) {
                    fsp += pen;
                    fsc += 1.0f;
                }
            }
        }
        sp += (double)fsp;
        sc += (double)fsc;
    };

    Slice s0, s1, s2;

    // ---- prologue: planes 0,1 unpacked; plane 2 in flight ----
    pref(0); unpack(s0);
    pref(1); unpack(s1);
    pref(2);

    // ---- 10 pipelined phases: unpack plane z+2, prefetch z+3, compute z ----
    unpack(s2); pref(3);  compute(s0, s1, s2, 0);
    unpack(s0); pref(4);  compute(s1, s2, s0, 1);
    unpack(s1); pref(5);  compute(s2, s0, s1, 2);
    unpack(s2); pref(6);  compute(s0, s1, s2, 3);
    unpack(s0); pref(7);  compute(s1, s2, s0, 4);
    unpack(s1); pref(8);  compute(s2, s0, s1, 5);
    unpack(s2); pref(9);  compute(s0, s1, s2, 6);
    unpack(s0); pref(10); compute(s1, s2, s0, 7);
    unpack(s1); pref(11); compute(s2, s0, s1, 8);
    unpack(s2);           compute(s0, s1, s2, 9);

    // ---- reduction ----
#pragma unroll
    for (int off = 32; off > 0; off >>= 1) {
        sp += __shfl_down(sp, off, 64);
        sc += __shfl_down(sc, off, 64);
    }

    __shared__ double lsp[4], lsc[4];
    const int wave = tid >> 6, lane = tid & 63;
    if (lane == 0) { lsp[wave] = sp; lsc[wave] = sc; }
    __syncthreads();
    if (tid == 0) {
        double tp = lsp[0] + lsp[1] + lsp[2] + lsp[3];
        double tc = lsc[0] + lsc[1] + lsc[2] + lsc[3];
        if (use_partials) {
            acc[2 * blockIdx.x]     = tp;
            acc[2 * blockIdx.x + 1] = tc;
        } else {
            atomicAdd(&acc[0], tp);
            atomicAdd(&acc[1], tc);
        }
    }
}

__global__ __launch_bounds__(256) void curv_reduce(const double* __restrict__ part,
                                                   int nblocks, int use_partials,
                                                   float* __restrict__ out) {
    double sp = 0.0, sc = 0.0;
    if (use_partials) {
        for (int i = threadIdx.x; i < nblocks; i += 256) {
            sp += part[2 * i];
            sc += part[2 * i + 1];
        }
    } else if (threadIdx.x == 0) {
        sp = part[0]; sc = part[1];
    }
#pragma unroll
    for (int off = 32; off > 0; off >>= 1) {
        sp += __shfl_down(sp, off, 64);
        sc += __shfl_down(sc, off, 64);
    }
    __shared__ double lsp[4], lsc[4];
    const int wave = threadIdx.x >> 6, lane = threadIdx.x & 63;
    if (lane == 0) { lsp[wave] = sp; lsc[wave] = sc; }
    __syncthreads();
    if (threadIdx.x == 0) {
        double tp = lsp[0] + lsp[1] + lsp[2] + lsp[3];
        double tc = lsc[0] + lsc[1] + lsc[2] + lsc[3];
        out[0] = (float)(tp / (tc + 1e-8));
    }
}

extern "C" void kernel_launch(void* const* d_in, const int* in_sizes, int n_in,
                              void* d_out, int out_size, void* d_ws, size_t ws_size,
                              hipStream_t stream) {
    const float* phi = (const float*)d_in[0];
    float* out = (float*)d_out;
    double* acc = (double*)d_ws;

    const int use_partials = (ws_size >= (size_t)(2 * NBLOCKS) * sizeof(double)) ? 1 : 0;
    if (!use_partials) {
        hipMemsetAsync(d_ws, 0, 2 * sizeof(double), stream);
    }

    curv_main<<<NBLOCKS, 256, 0, stream>>>(phi, acc, use_partials);
    curv_reduce<<<1, 256, 0, stream>>>(acc, NBLOCKS, use_partials, out);
}